// Round 2
// baseline (248.470 us; speedup 1.0000x reference)
//
#include <hip/hip_runtime.h>

#define B_  4
#define C_  16
#define H_  256
#define W_  256
#define CO_ 16
#define KS_ 3
#define KK_ 9

__global__ __launch_bounds__(256) void deform_loss_kernel(
    const float* __restrict__ off, const float* __restrict__ inp,
    const float* __restrict__ ker, const float* __restrict__ tgt,
    float* __restrict__ out)
{
    const int idx = blockIdx.x * blockDim.x + threadIdx.x;
    float part = 0.f;

    if (idx < B_ * H_ * W_) {
        const int w  = idx & (W_ - 1);
        const int h  = (idx >> 8) & (H_ - 1);
        const int b  = idx >> 16;
        const int hw = h * W_ + w;

        const float* offb = off + (size_t)b * (2 * KK_ * H_ * W_);
        const float* inpb = inp + (size_t)b * (C_ * H_ * W_);

        float acc[CO_];
#pragma unroll
        for (int o = 0; o < CO_; o++) acc[o] = 0.f;

        for (int kk = 0; kk < KK_; kk++) {
            const int ki = kk / KS_;
            const int kj = kk % KS_;

            const float dy = offb[(2 * kk)     * H_ * W_ + hw];
            const float dx = offb[(2 * kk + 1) * H_ * W_ + hw];

            const float y = dy + (float)(h - 1 + ki);
            const float x = dx + (float)(w - 1 + kj);

            const float y0f = floorf(y);
            const float x0f = floorf(x);
            const int   y0  = (int)y0f;
            const int   x0  = (int)x0f;
            const float wy  = y - y0f;
            const float wx  = x - x0f;

            float w00 = (1.f - wy) * (1.f - wx);
            float w01 = (1.f - wy) * wx;
            float w10 = wy * (1.f - wx);
            float w11 = wy * wx;

            // zero-padding: fold validity into weights, clamp indices so all
            // loads stay in-bounds (no speculative OOB reads)
            const bool v0y = ((unsigned)y0       < (unsigned)H_);
            const bool v1y = ((unsigned)(y0 + 1) < (unsigned)H_);
            const bool v0x = ((unsigned)x0       < (unsigned)W_);
            const bool v1x = ((unsigned)(x0 + 1) < (unsigned)W_);

            w00 = (v0y & v0x) ? w00 : 0.f;
            w01 = (v0y & v1x) ? w01 : 0.f;
            w10 = (v1y & v0x) ? w10 : 0.f;
            w11 = (v1y & v1x) ? w11 : 0.f;

            const int y0c = min(max(y0,     0), H_ - 1);
            const int y1c = min(max(y0 + 1, 0), H_ - 1);
            const int x0c = min(max(x0,     0), W_ - 1);
            const int x1c = min(max(x0 + 1, 0), W_ - 1);

            const int i00 = y0c * W_ + x0c;
            const int i01 = y0c * W_ + x1c;
            const int i10 = y1c * W_ + x0c;
            const int i11 = y1c * W_ + x1c;

            for (int c = 0; c < C_; c++) {
                const float* p = inpb + c * H_ * W_;
                const float v00 = p[i00];
                const float v01 = p[i01];
                const float v10 = p[i10];
                const float v11 = p[i11];
                const float s = v00 * w00 + v01 * w01 + v10 * w10 + v11 * w11;
#pragma unroll
                for (int o = 0; o < CO_; o++)
                    acc[o] = fmaf(s, ker[(o * C_ + c) * KK_ + kk], acc[o]);
            }
        }

        const float* tb = tgt + (size_t)b * (CO_ * H_ * W_);
#pragma unroll
        for (int o = 0; o < CO_; o++) {
            const float d = acc[o] - tb[o * H_ * W_ + hw];
            part = fmaf(d, d, part);
        }
        part *= (1.0f / (float)((size_t)B_ * CO_ * H_ * W_));
    }

    // wave-level reduction (wave64), then one atomic per wave
#pragma unroll
    for (int s = 32; s > 0; s >>= 1)
        part += __shfl_down(part, s, 64);

    if ((threadIdx.x & 63) == 0)
        atomicAdd(out, part);
}

extern "C" void kernel_launch(void* const* d_in, const int* in_sizes, int n_in,
                              void* d_out, int out_size, void* d_ws, size_t ws_size,
                              hipStream_t stream) {
    const float* offsets = (const float*)d_in[0];
    const float* input   = (const float*)d_in[1];
    const float* ker     = (const float*)d_in[2];
    const float* target  = (const float*)d_in[3];
    float* out = (float*)d_out;

    // d_out is poisoned before every launch — zero the accumulator
    hipMemsetAsync(out, 0, sizeof(float), stream);

    const int total  = B_ * H_ * W_;
    const int block  = 256;
    const int grid   = (total + block - 1) / block;
    deform_loss_kernel<<<grid, block, 0, stream>>>(offsets, input, ker, target, out);
}

// Round 4
// 202.504 us; speedup vs baseline: 1.2270x; 1.2270x over previous
//
#include <hip/hip_runtime.h>

#define B_  4
#define C_  16
#define H_  256
#define W_  256
#define CO_ 16
#define KS_ 3
#define KK_ 9
#define HW_ (H_ * W_)

// ---------------- Kernel 1: NCHW -> NHWC transpose into workspace ----------
__global__ __launch_bounds__(256) void transpose_nhwc(
    const float* __restrict__ inp, float* __restrict__ wsp)
{
    __shared__ float tile[256][C_ + 1];
    const int base = blockIdx.x * 256;      // flat (b*HW + hw) base
    const int t    = threadIdx.x;
    const int e    = base + t;
    const int b    = e >> 16;
    const int hw   = e & (HW_ - 1);
    const float* src = inp + (size_t)b * (C_ * HW_) + hw;
#pragma unroll
    for (int c = 0; c < C_; c++)
        tile[t][c] = src[c * HW_];          // coalesced reads per c-plane
    __syncthreads();
    // tile covers 256*16 floats = 1024 float4s; write fully coalesced
    float4* dst = (float4*)(wsp + (size_t)base * C_);
#pragma unroll
    for (int q = 0; q < 4; q++) {
        const int f   = q * 256 + t;        // float4 index within tile
        const int hwl = f >> 2;
        const int c0  = (f & 3) * 4;
        dst[f] = make_float4(tile[hwl][c0], tile[hwl][c0 + 1],
                             tile[hwl][c0 + 2], tile[hwl][c0 + 3]);
    }
}

// ---------------- Kernel 2: deform-conv + MSE, NHWC gathers ----------------
__global__ __launch_bounds__(256) void deform_loss_nhwc(
    const float* __restrict__ off, const float* __restrict__ wsp,
    const float* __restrict__ ker, const float* __restrict__ tgt,
    float* __restrict__ out)
{
    // XCD swizzle: HW round-robins blocks across 8 XCDs; make blocks that
    // share an XCD cover a contiguous (b,h) span so row re-reads hit the
    // same L2. Bijection on [0, 1024): xcd = blk&7 gets rows xcd*128..+127.
    const int bh = (blockIdx.x & 7) * 128 + (blockIdx.x >> 3);
    const int b  = bh >> 8;
    const int h  = bh & (H_ - 1);
    const int w  = threadIdx.x;
    const int hw = h * W_ + w;

    const float* offb = off + (size_t)b * (2 * KK_ * HW_) + hw;
    const float* inb  = wsp + (size_t)b * (HW_ * C_);

    float acc[CO_];
#pragma unroll
    for (int o = 0; o < CO_; o++) acc[o] = 0.f;

    for (int kk = 0; kk < KK_; kk++) {
        const float dy = offb[(2 * kk)     * HW_];
        const float dx = offb[(2 * kk + 1) * HW_];

        const float y = dy + (float)(h - 1 + kk / KS_);
        const float x = dx + (float)(w - 1 + kk % KS_);

        const float y0f = floorf(y);
        const float x0f = floorf(x);
        const int   y0  = (int)y0f;
        const int   x0  = (int)x0f;
        const float wy  = y - y0f;
        const float wx  = x - x0f;

        float w00 = (1.f - wy) * (1.f - wx);
        float w01 = (1.f - wy) * wx;
        float w10 = wy * (1.f - wx);
        float w11 = wy * wx;

        const bool v0y = ((unsigned)y0       < (unsigned)H_);
        const bool v1y = ((unsigned)(y0 + 1) < (unsigned)H_);
        const bool v0x = ((unsigned)x0       < (unsigned)W_);
        const bool v1x = ((unsigned)(x0 + 1) < (unsigned)W_);

        w00 = (v0y & v0x) ? w00 : 0.f;
        w01 = (v0y & v1x) ? w01 : 0.f;
        w10 = (v1y & v0x) ? w10 : 0.f;
        w11 = (v1y & v1x) ? w11 : 0.f;

        const int y0c = min(max(y0,     0), H_ - 1);
        const int y1c = min(max(y0 + 1, 0), H_ - 1);
        const int x0c = min(max(x0,     0), W_ - 1);
        const int x1c = min(max(x0 + 1, 0), W_ - 1);

        const float4* p00 = (const float4*)(inb + (size_t)(y0c * W_ + x0c) * C_);
        const float4* p01 = (const float4*)(inb + (size_t)(y0c * W_ + x1c) * C_);
        const float4* p10 = (const float4*)(inb + (size_t)(y1c * W_ + x0c) * C_);
        const float4* p11 = (const float4*)(inb + (size_t)(y1c * W_ + x1c) * C_);

        float sc[C_];
#pragma unroll
        for (int q = 0; q < 4; q++) {          // 4 float4s = 16 channels
            const float4 a = p00[q];
            const float4 bq = p01[q];
            const float4 cq = p10[q];
            const float4 dq = p11[q];
            sc[q * 4 + 0] = a.x * w00 + bq.x * w01 + cq.x * w10 + dq.x * w11;
            sc[q * 4 + 1] = a.y * w00 + bq.y * w01 + cq.y * w10 + dq.y * w11;
            sc[q * 4 + 2] = a.z * w00 + bq.z * w01 + cq.z * w10 + dq.z * w11;
            sc[q * 4 + 3] = a.w * w00 + bq.w * w01 + cq.w * w10 + dq.w * w11;
        }

#pragma unroll
        for (int c = 0; c < C_; c++) {
            const float s = sc[c];
#pragma unroll
            for (int o = 0; o < CO_; o++)
                acc[o] = fmaf(s, ker[(o * C_ + c) * KK_ + kk], acc[o]);
        }
    }

    const float* tb = tgt + (size_t)b * (CO_ * HW_) + hw;
    float part = 0.f;
#pragma unroll
    for (int o = 0; o < CO_; o++) {
        const float d = acc[o] - tb[o * HW_];
        part = fmaf(d, d, part);
    }
    part *= (1.0f / (float)((size_t)B_ * CO_ * HW_));

#pragma unroll
    for (int s = 32; s > 0; s >>= 1)
        part += __shfl_down(part, s, 64);
    if ((threadIdx.x & 63) == 0)
        atomicAdd(out, part);
}

// ---------------- Fallback (round-1 NCHW kernel, used if ws too small) -----
__global__ __launch_bounds__(256) void deform_loss_kernel(
    const float* __restrict__ off, const float* __restrict__ inp,
    const float* __restrict__ ker, const float* __restrict__ tgt,
    float* __restrict__ out)
{
    const int idx = blockIdx.x * blockDim.x + threadIdx.x;
    float part = 0.f;
    if (idx < B_ * H_ * W_) {
        const int w  = idx & (W_ - 1);
        const int h  = (idx >> 8) & (H_ - 1);
        const int b  = idx >> 16;
        const int hw = h * W_ + w;
        const float* offb = off + (size_t)b * (2 * KK_ * HW_);
        const float* inpb = inp + (size_t)b * (C_ * HW_);
        float acc[CO_];
#pragma unroll
        for (int o = 0; o < CO_; o++) acc[o] = 0.f;
        for (int kk = 0; kk < KK_; kk++) {
            const float dy = offb[(2 * kk)     * HW_ + hw];
            const float dx = offb[(2 * kk + 1) * HW_ + hw];
            const float y = dy + (float)(h - 1 + kk / KS_);
            const float x = dx + (float)(w - 1 + kk % KS_);
            const float y0f = floorf(y);
            const float x0f = floorf(x);
            const int   y0  = (int)y0f;
            const int   x0  = (int)x0f;
            const float wy  = y - y0f;
            const float wx  = x - x0f;
            float w00 = (1.f - wy) * (1.f - wx);
            float w01 = (1.f - wy) * wx;
            float w10 = wy * (1.f - wx);
            float w11 = wy * wx;
            const bool v0y = ((unsigned)y0       < (unsigned)H_);
            const bool v1y = ((unsigned)(y0 + 1) < (unsigned)H_);
            const bool v0x = ((unsigned)x0       < (unsigned)W_);
            const bool v1x = ((unsigned)(x0 + 1) < (unsigned)W_);
            w00 = (v0y & v0x) ? w00 : 0.f;
            w01 = (v0y & v1x) ? w01 : 0.f;
            w10 = (v1y & v0x) ? w10 : 0.f;
            w11 = (v1y & v1x) ? w11 : 0.f;
            const int i00 = min(max(y0,0),H_-1)*W_ + min(max(x0,0),W_-1);
            const int i01 = min(max(y0,0),H_-1)*W_ + min(max(x0+1,0),W_-1);
            const int i10 = min(max(y0+1,0),H_-1)*W_ + min(max(x0,0),W_-1);
            const int i11 = min(max(y0+1,0),H_-1)*W_ + min(max(x0+1,0),W_-1);
            for (int c = 0; c < C_; c++) {
                const float* p = inpb + c * HW_;
                const float s = p[i00]*w00 + p[i01]*w01 + p[i10]*w10 + p[i11]*w11;
#pragma unroll
                for (int o = 0; o < CO_; o++)
                    acc[o] = fmaf(s, ker[(o * C_ + c) * KK_ + kk], acc[o]);
            }
        }
        const float* tb = tgt + (size_t)b * (CO_ * HW_);
#pragma unroll
        for (int o = 0; o < CO_; o++) {
            const float d = acc[o] - tb[o * HW_ + hw];
            part = fmaf(d, d, part);
        }
        part *= (1.0f / (float)((size_t)B_ * CO_ * HW_));
    }
#pragma unroll
    for (int s = 32; s > 0; s >>= 1)
        part += __shfl_down(part, s, 64);
    if ((threadIdx.x & 63) == 0)
        atomicAdd(out, part);
}

extern "C" void kernel_launch(void* const* d_in, const int* in_sizes, int n_in,
                              void* d_out, int out_size, void* d_ws, size_t ws_size,
                              hipStream_t stream) {
    const float* offsets = (const float*)d_in[0];
    const float* input   = (const float*)d_in[1];
    const float* ker     = (const float*)d_in[2];
    const float* target  = (const float*)d_in[3];
    float* out = (float*)d_out;

    hipMemsetAsync(out, 0, sizeof(float), stream);

    const size_t need = (size_t)B_ * HW_ * C_ * sizeof(float);  // 16.78 MB
    if (ws_size >= need) {
        float* wsp = (float*)d_ws;
        transpose_nhwc<<<(B_ * HW_) / 256, 256, 0, stream>>>(input, wsp);
        deform_loss_nhwc<<<B_ * H_, 256, 0, stream>>>(offsets, wsp, ker, target, out);
    } else {
        const int total = B_ * H_ * W_;
        deform_loss_kernel<<<(total + 255) / 256, 256, 0, stream>>>(
            offsets, input, ker, target, out);
    }
}